// Round 1
// baseline (516.311 us; speedup 1.0000x reference)
//
#include <hip/hip_runtime.h>
#include <math.h>

// Exact GELU: x * 0.5 * (1 + erf(x / sqrt(2)))  (approximate=False in JAX ref)
__device__ __forceinline__ float gelu_f(float v) {
    return 0.5f * v * (1.0f + erff(v * 0.70710678118654752f));
}

__global__ __launch_bounds__(256) void mlp_fused_kernel(
    const float* __restrict__ x,
    const float* __restrict__ alpha,
    const float* __restrict__ beta,
    const float* __restrict__ gamma,
    const float* __restrict__ g,
    const float* __restrict__ W1, const float* __restrict__ b1,
    const float* __restrict__ W2, const float* __restrict__ b2,
    const float* __restrict__ Wres, const float* __restrict__ bres,
    const float* __restrict__ W6, const float* __restrict__ b6,
    float* __restrict__ out, int B)
{
    int row = blockIdx.x * blockDim.x + threadIdx.x;
    if (row >= B) return;

    // ---- load row (73 floats, contiguous per thread) ----
    const float* xp = x + (size_t)row * 73;
    float xr[73];
    #pragma unroll
    for (int k = 0; k < 73; ++k) xr[k] = xp[k];

    // ---- feature embed (gather) + per-column scale ----
    int ia = (int)xr[0];
    int ib = (int)xr[1];
    xr[0] = alpha[ia];
    xr[1] = beta[ib];
    #pragma unroll
    for (int j = 3; j < 23; ++j) xr[j] *= gamma[j];

    // ---- layer 1: 73 -> 64, GELU.  4 accumulators for ILP; weight
    //      addresses are wave-uniform -> compiler emits scalar loads. ----
    float h1[64];
    for (int o = 0; o < 64; o += 4) {
        float a0 = b1[o + 0], a1 = b1[o + 1], a2 = b1[o + 2], a3 = b1[o + 3];
        const float* w = W1 + (size_t)o * 73;
        #pragma unroll
        for (int k = 0; k < 73; ++k) {
            float xv = xr[k];
            a0 = fmaf(xv, w[k +   0], a0);
            a1 = fmaf(xv, w[k +  73], a1);
            a2 = fmaf(xv, w[k + 146], a2);
            a3 = fmaf(xv, w[k + 219], a3);
        }
        h1[o + 0] = gelu_f(a0);
        h1[o + 1] = gelu_f(a1);
        h1[o + 2] = gelu_f(a2);
        h1[o + 3] = gelu_f(a3);
    }

    // ---- layer 2: 64 -> 32, GELU ----
    float h2[32];
    for (int o = 0; o < 32; o += 4) {
        float a0 = b2[o + 0], a1 = b2[o + 1], a2 = b2[o + 2], a3 = b2[o + 3];
        const float* w = W2 + (size_t)o * 64;
        #pragma unroll
        for (int k = 0; k < 64; ++k) {
            float xv = h1[k];
            a0 = fmaf(xv, w[k +   0], a0);
            a1 = fmaf(xv, w[k +  64], a1);
            a2 = fmaf(xv, w[k + 128], a2);
            a3 = fmaf(xv, w[k + 192], a3);
        }
        h2[o + 0] = gelu_f(a0);
        h2[o + 1] = gelu_f(a1);
        h2[o + 2] = gelu_f(a2);
        h2[o + 3] = gelu_f(a3);
    }

    // ---- residual layer: 32 -> 32, pre-act = h2@Wres^T + bres + h2, GELU ----
    float h3[32];
    for (int o = 0; o < 32; o += 4) {
        float a0 = bres[o + 0] + h2[o + 0];
        float a1 = bres[o + 1] + h2[o + 1];
        float a2 = bres[o + 2] + h2[o + 2];
        float a3 = bres[o + 3] + h2[o + 3];
        const float* w = Wres + (size_t)o * 32;
        #pragma unroll
        for (int k = 0; k < 32; ++k) {
            float xv = h2[k];
            a0 = fmaf(xv, w[k +  0], a0);
            a1 = fmaf(xv, w[k + 32], a1);
            a2 = fmaf(xv, w[k + 64], a2);
            a3 = fmaf(xv, w[k + 96], a3);
        }
        h3[o + 0] = gelu_f(a0);
        h3[o + 1] = gelu_f(a1);
        h3[o + 2] = gelu_f(a2);
        h3[o + 3] = gelu_f(a3);
    }

    // ---- output: 32 -> 1 ----
    float acc = b6[0] + g[0];
    #pragma unroll
    for (int k = 0; k < 32; ++k) acc = fmaf(h3[k], W6[k], acc);
    out[row] = acc;
}

extern "C" void kernel_launch(void* const* d_in, const int* in_sizes, int n_in,
                              void* d_out, int out_size, void* d_ws, size_t ws_size,
                              hipStream_t stream) {
    const float* x     = (const float*)d_in[0];
    const float* alpha = (const float*)d_in[1];
    const float* beta  = (const float*)d_in[2];
    const float* gamma = (const float*)d_in[3];
    const float* g     = (const float*)d_in[4];
    const float* W1    = (const float*)d_in[5];
    const float* b1    = (const float*)d_in[6];
    const float* W2    = (const float*)d_in[7];
    const float* b2    = (const float*)d_in[8];
    const float* Wres  = (const float*)d_in[9];
    const float* bres  = (const float*)d_in[10];
    const float* W6    = (const float*)d_in[11];
    const float* b6    = (const float*)d_in[12];
    float* out = (float*)d_out;

    int B = out_size;  // one output per row
    int block = 256;
    int grid = (B + block - 1) / block;
    mlp_fused_kernel<<<grid, block, 0, stream>>>(x, alpha, beta, gamma, g,
                                                 W1, b1, W2, b2, Wres, bres,
                                                 W6, b6, out, B);
}

// Round 2
// 457.630 us; speedup vs baseline: 1.1282x; 1.1282x over previous
//
#include <hip/hip_runtime.h>
#include <math.h>

// Exact GELU: x * 0.5 * (1 + erf(x / sqrt(2)))  (approximate=False in JAX ref)
__device__ __forceinline__ float gelu_f(float v) {
    return 0.5f * v * (1.0f + erff(v * 0.70710678118654752f));
}

// 2 waves/EU min -> VGPR capped at 256; all per-thread arrays must be
// statically indexed (every loop fully unrolled) so they live in VGPRs,
// not scratch.  Round-1 lesson: without the unrolls, h1/h2/h3/xr spilled
// (VGPR=60, WRITE_SIZE=260MB of spill traffic).
__global__ __launch_bounds__(256, 2) void mlp_fused_kernel(
    const float* __restrict__ x,
    const float* __restrict__ alpha,
    const float* __restrict__ beta,
    const float* __restrict__ gamma,
    const float* __restrict__ g,
    const float* __restrict__ W1, const float* __restrict__ b1,
    const float* __restrict__ W2, const float* __restrict__ b2,
    const float* __restrict__ Wres, const float* __restrict__ bres,
    const float* __restrict__ W6, const float* __restrict__ b6,
    float* __restrict__ out, int B)
{
    int row = blockIdx.x * blockDim.x + threadIdx.x;
    if (row >= B) return;

    // ---- load row (73 floats, contiguous per thread) ----
    const float* xp = x + (size_t)row * 73;
    float xr[73];
    #pragma unroll
    for (int k = 0; k < 73; ++k) xr[k] = xp[k];

    // ---- feature embed (gather) + per-column scale ----
    int ia = (int)xr[0];
    int ib = (int)xr[1];
    xr[0] = alpha[ia];
    xr[1] = beta[ib];
    #pragma unroll
    for (int j = 3; j < 23; ++j) xr[j] *= gamma[j];

    // ---- layer 1: 73 -> 64, GELU ----
    float h1[64];
    #pragma unroll
    for (int o = 0; o < 64; o += 4) {
        float a0 = b1[o + 0], a1 = b1[o + 1], a2 = b1[o + 2], a3 = b1[o + 3];
        const float* w = W1 + (size_t)o * 73;
        #pragma unroll
        for (int k = 0; k < 73; ++k) {
            float xv = xr[k];
            a0 = fmaf(xv, w[k +   0], a0);
            a1 = fmaf(xv, w[k +  73], a1);
            a2 = fmaf(xv, w[k + 146], a2);
            a3 = fmaf(xv, w[k + 219], a3);
        }
        h1[o + 0] = gelu_f(a0);
        h1[o + 1] = gelu_f(a1);
        h1[o + 2] = gelu_f(a2);
        h1[o + 3] = gelu_f(a3);
    }

    // ---- layer 2: 64 -> 32, GELU ----
    float h2[32];
    #pragma unroll
    for (int o = 0; o < 32; o += 4) {
        float a0 = b2[o + 0], a1 = b2[o + 1], a2 = b2[o + 2], a3 = b2[o + 3];
        const float* w = W2 + (size_t)o * 64;
        #pragma unroll
        for (int k = 0; k < 64; ++k) {
            float xv = h1[k];
            a0 = fmaf(xv, w[k +   0], a0);
            a1 = fmaf(xv, w[k +  64], a1);
            a2 = fmaf(xv, w[k + 128], a2);
            a3 = fmaf(xv, w[k + 192], a3);
        }
        h2[o + 0] = gelu_f(a0);
        h2[o + 1] = gelu_f(a1);
        h2[o + 2] = gelu_f(a2);
        h2[o + 3] = gelu_f(a3);
    }

    // ---- residual layer: 32 -> 32, pre-act = h2@Wres^T + bres + h2, GELU ----
    float h3[32];
    #pragma unroll
    for (int o = 0; o < 32; o += 4) {
        float a0 = bres[o + 0] + h2[o + 0];
        float a1 = bres[o + 1] + h2[o + 1];
        float a2 = bres[o + 2] + h2[o + 2];
        float a3 = bres[o + 3] + h2[o + 3];
        const float* w = Wres + (size_t)o * 32;
        #pragma unroll
        for (int k = 0; k < 32; ++k) {
            float xv = h2[k];
            a0 = fmaf(xv, w[k +  0], a0);
            a1 = fmaf(xv, w[k + 32], a1);
            a2 = fmaf(xv, w[k + 64], a2);
            a3 = fmaf(xv, w[k + 96], a3);
        }
        h3[o + 0] = gelu_f(a0);
        h3[o + 1] = gelu_f(a1);
        h3[o + 2] = gelu_f(a2);
        h3[o + 3] = gelu_f(a3);
    }

    // ---- output: 32 -> 1 ----
    float acc = b6[0] + g[0];
    #pragma unroll
    for (int k = 0; k < 32; ++k) acc = fmaf(h3[k], W6[k], acc);
    out[row] = acc;
}

extern "C" void kernel_launch(void* const* d_in, const int* in_sizes, int n_in,
                              void* d_out, int out_size, void* d_ws, size_t ws_size,
                              hipStream_t stream) {
    const float* x     = (const float*)d_in[0];
    const float* alpha = (const float*)d_in[1];
    const float* beta  = (const float*)d_in[2];
    const float* gamma = (const float*)d_in[3];
    const float* g     = (const float*)d_in[4];
    const float* W1    = (const float*)d_in[5];
    const float* b1    = (const float*)d_in[6];
    const float* W2    = (const float*)d_in[7];
    const float* b2    = (const float*)d_in[8];
    const float* Wres  = (const float*)d_in[9];
    const float* bres  = (const float*)d_in[10];
    const float* W6    = (const float*)d_in[11];
    const float* b6    = (const float*)d_in[12];
    float* out = (float*)d_out;

    int B = out_size;  // one output per row
    int block = 256;
    int grid = (B + block - 1) / block;
    mlp_fused_kernel<<<grid, block, 0, stream>>>(x, alpha, beta, gamma, g,
                                                 W1, b1, W2, b2, Wres, bres,
                                                 W6, b6, out, B);
}